// Round 13
// baseline (306.372 us; speedup 1.0000x reference)
//
#include <hip/hip_runtime.h>

#define N_NODES 100000
#define N_HEDGES 30000
#define N_PINS 400000
#define NPN 100096   // padded node rows (= 782*128)
#define OVF_CAP 8192
#define SCAN_BH 118  // ceil(30000/256)
#define SCAN_BN 391  // ceil(100000/256)
#define SCAN_B (SCAN_BH + SCAN_BN)
#define TB 1563      // transform blocks = ceil(100000/64)

typedef __attribute__((ext_vector_type(8))) short bf16x8;
typedef __attribute__((ext_vector_type(4))) float f32x4;
typedef unsigned short ushort_t;

__device__ __forceinline__ unsigned short f2bf(float f) {
  unsigned int u = __float_as_uint(f);
  u += 0x7FFF + ((u >> 16) & 1);
  return (unsigned short)(u >> 16);
}
__device__ __forceinline__ float bf2f(unsigned short s) {
  return __uint_as_float(((unsigned int)s) << 16);
}
__device__ __forceinline__ void gload16(const void* g, void* l) {
  __builtin_amdgcn_global_load_lds(
      (const __attribute__((address_space(1))) unsigned int*)g,
      (__attribute__((address_space(3))) unsigned int*)l, 16, 0, 0);
}

// ---------------------------------------------------------------------------
// fused front-end (proven): atomics issued first, rank2 written last;
// vectorized conv; weight prep. Atomic-throughput-bound (~47us floor).
// ---------------------------------------------------------------------------
__global__ __launch_bounds__(256) void fused_front(
    const float* __restrict__ x0_in, ushort_t* __restrict__ x0b,
    const int* __restrict__ node_idx, const int* __restrict__ hedge_idx,
    int* __restrict__ cntN, int* __restrict__ cntH, unsigned* __restrict__ rank2,
    const float* __restrict__ Kw, const float* __restrict__ Vw,
    const float* __restrict__ Qw, const float* __restrict__ W1,
    const float* __restrict__ W2, ushort_t* __restrict__ Vvqsw,
    ushort_t* __restrict__ W1sw, ushort_t* __restrict__ W2sw) {
  int gsz = gridDim.x * 256;
  int tid = blockIdx.x * 256 + threadIdx.x;
  int rn = 0, rh = 0;
  bool hasPin = tid < N_PINS;
  if (hasPin) {
    int n_i = node_idx[tid], h_i = hedge_idx[tid];
    rn = atomicAdd(&cntN[n_i], 1);
    rh = atomicAdd(&cntH[h_i], 1);
  }
  for (int i = tid; i < N_NODES * 16; i += gsz) {
    const float4* s = (const float4*)x0_in + (size_t)i * 2;
    float4 a = s[0], b = s[1];
    uint4 o;
    o.x = ((unsigned)f2bf(a.y) << 16) | f2bf(a.x);
    o.y = ((unsigned)f2bf(a.w) << 16) | f2bf(a.z);
    o.z = ((unsigned)f2bf(b.y) << 16) | f2bf(b.x);
    o.w = ((unsigned)f2bf(b.w) << 16) | f2bf(b.z);
    ((uint4*)x0b)[i] = o;
  }
  for (int i = tid; i < 4 * 144 * 128; i += gsz) {
    int b = i / 18432, r = i % 18432, c = r >> 7, d = r & 127;
    float v;
    if (c < 128) {
      v = Vw[((b * 4 + (c >> 5)) * 128 + d) * 32 + (c & 31)];
    } else if (c < 132) {
      int h = c - 128;
      const float* kp = Kw + ((b * 4 + h) * 128 + d) * 32;
      const float* qp = Qw + (b * 4 + h) * 32;
      float s = 0.f;
      for (int k = 0; k < 32; ++k) s += kp[k] * qp[k];
      v = s;
    } else {
      v = 0.f;
    }
    int L = (c * 256 + d * 2) ^ ((c & 7) << 4);
    Vvqsw[b * 18432 + L / 2] = f2bf(v);
  }
  for (int i = tid; i < 4 * 128 * 128; i += gsz) {
    int b = i >> 14, r = i & 16383, c = r >> 7, k = r & 127;
    int L = (c * 256 + k * 2) ^ ((c & 7) << 4);
    int idx = b * 16384 + L / 2;
    W1sw[idx] = f2bf(W1[b * 16384 + k * 128 + c]);
    W2sw[idx] = f2bf(W2[b * 16384 + k * 128 + c]);
  }
  if (hasPin) rank2[tid] = ((unsigned)rh << 16) | (unsigned)rn;
}

// ---------------------------------------------------------------------------
// scan_tf (proven round 12): merged scan + transform(b0).
// ---------------------------------------------------------------------------
__global__ __launch_bounds__(256) void scan_tf(
    const int* __restrict__ cntH, int2* __restrict__ segH, int* __restrict__ ovfH,
    const int* __restrict__ cntN, int2* __restrict__ segN, int* __restrict__ ovfN,
    int* __restrict__ gctr, const ushort_t* __restrict__ xb,
    const ushort_t* __restrict__ Bsw, ushort_t* __restrict__ Vxb,
    float* __restrict__ lg) {
  __shared__ char Blds[36864];
  __shared__ char Olds[16384];
  __shared__ int wsum[4];
  __shared__ int bbase;
  int t = threadIdx.x, l = t & 63, w = t >> 6;

  if ((int)blockIdx.x < SCAN_B) {
    bool isH = (int)blockIdx.x < SCAN_BH;
    const int* cnt = isH ? cntH : cntN;
    int2* seg = isH ? segH : segN;
    int* ovf = isH ? ovfH : ovfN;
    int* g = gctr + (isH ? 0 : 1);
    int* oc = gctr + (isH ? 2 : 3);
    int thresh = isH ? 32 : 16;
    int n = isH ? N_HEDGES : N_NODES;
    int i = (isH ? (int)blockIdx.x : (int)blockIdx.x - SCAN_BH) * 256 + t;
    int lane = t & 63, wid = t >> 6;
    int v = (i < n) ? cnt[i] : 0;
    int sc = v;
#pragma unroll
    for (int s = 1; s < 64; s <<= 1) {
      int tv = __shfl_up(sc, s);
      if (lane >= s) sc += tv;
    }
    if (lane == 63) wsum[wid] = sc;
    __syncthreads();
    if (t == 0) {
      int s0 = wsum[0], s1 = wsum[1], s2 = wsum[2], s3 = wsum[3];
      wsum[0] = 0; wsum[1] = s0; wsum[2] = s0 + s1; wsum[3] = s0 + s1 + s2;
      bbase = atomicAdd(g, s0 + s1 + s2 + s3);
    }
    __syncthreads();
    if (i < n) {
      int st = bbase + wsum[wid] + (sc - v);
      seg[i] = make_int2(st, v);
      if (v > thresh) {
        int k = atomicAdd(oc, 1);
        if (k < OVF_CAP) ovf[k] = i;
      }
    }
    return;
  }

  size_t r0 = (size_t)((int)blockIdx.x - SCAN_B) * 64;
#pragma unroll
  for (int it = 0; it < 9; ++it) {
    int off = it * 4096 + w * 1024 + l * 16;
    gload16((const char*)Bsw + off, Blds + off);
  }
  __syncthreads();

  f32x4 acc[9];
#pragma unroll
  for (int ct = 0; ct < 9; ++ct) acc[ct] = (f32x4){0.f, 0.f, 0.f, 0.f};
  int swz = (l & 7) << 4;
  int lbase = (l & 15) * 256 + (l >> 4) * 16;
  const ushort_t* abase = xb + (r0 + w * 16 + (l & 15)) * 128 + (l >> 4) * 8;
#pragma unroll
  for (int kk = 0; kk < 4; ++kk) {
    bf16x8 a = *(const bf16x8*)(abase + kk * 32);
#pragma unroll
    for (int ct = 0; ct < 9; ++ct) {
      bf16x8 b = *(const bf16x8*)(Blds + ((ct * 4096 + kk * 64 + lbase) ^ swz));
      acc[ct] = __builtin_amdgcn_mfma_f32_16x16x32_bf16(a, b, acc[ct], 0, 0, 0);
    }
  }
  if ((l & 15) < 4) {
    size_t rb = r0 + w * 16 + (l >> 4) * 4;
#pragma unroll
    for (int j = 0; j < 4; ++j) lg[(rb + j) * 4 + (l & 15)] = acc[8][j];
  }
  int row64 = w * 16 + (l >> 4) * 4;
#pragma unroll
  for (int ct = 0; ct < 8; ++ct) {
    int c2 = (ct * 16 + (l & 15)) * 2;
#pragma unroll
    for (int j = 0; j < 4; ++j) {
      int r = row64 + j;
      int addr = (r * 256 + c2) ^ ((r & 0xC) << 3);
      *(ushort_t*)(Olds + addr) = f2bf(acc[ct][j]);
    }
  }
  __syncthreads();
#pragma unroll
  for (int it = 0; it < 4; ++it) {
    int L = it * 4096 + t * 16;
    int r = L >> 8;
    int phys = L ^ ((r & 0xC) << 3);
    *(uint4*)((char*)Vxb + r0 * 256 + L) = *(const uint4*)(Olds + phys);
  }
}

// ---------------------------------------------------------------------------
// fill, atomic-free (proven)
// ---------------------------------------------------------------------------
__global__ __launch_bounds__(256) void csr_fill(
    const int* __restrict__ node_idx, const int* __restrict__ hedge_idx,
    const unsigned* __restrict__ rank2, const int2* __restrict__ segN,
    const int2* __restrict__ segH, int* __restrict__ pinsN,
    int* __restrict__ pinsH) {
  int e = blockIdx.x * 256 + threadIdx.x;
  if (e < N_PINS) {
    int n = node_idx[e], h = hedge_idx[e];
    unsigned r2 = rank2[e];
    pinsH[segH[h].x + (int)(r2 >> 16)] = n;
    pinsN[segN[n].x + (int)(r2 & 0xffffu)] = h;
  }
}

// ---------------------------------------------------------------------------
// attention (proven round-10): grouped, L lanes/target, one-shot softmax
// for deg<=L, overflow fallback for deg>L. L=16 nodes / L=32 hedges.
// ---------------------------------------------------------------------------
template <int L>
__global__ __launch_bounds__(256) void attn_g(
    const ushort_t* __restrict__ Vxb, const float* __restrict__ lg,
    const int2* __restrict__ seg, const int* __restrict__ pins,
    const float* __restrict__ Qflat, const float* __restrict__ g0,
    const float* __restrict__ be0, ushort_t* __restrict__ xmidb, int n_tgt,
    int mainBlocks, const int* __restrict__ ovf, const int* __restrict__ ovfcnt) {
  constexpr int G = 64 / L;
  constexpr int C = 128 / L;
  __shared__ float wl[4][G][L][4];
  __shared__ int pl[4][G][L];
  int wid = threadIdx.x >> 6, lane = threadIdx.x & 63;
  const char* vb = (const char*)Vxb;

  if ((int)blockIdx.x < mainBlocks) {
    int g = lane / L, li = lane % L;
    int tg = ((int)blockIdx.x * 4 + wid) * G + g;
    bool tval = tg < n_tgt;
    int2 sc = tval ? seg[tg] : make_int2(0, 0);
    int base = sc.x, deg = sc.y;
    bool fast = deg <= L;
    int mydeg = (tval && fast) ? deg : 0;
    bool act = li < mydeg;
    int p = act ? pins[base + li] : 0;
    float4 l4;
    if (act) l4 = *(const float4*)(lg + p * 4);
    else l4 = make_float4(-3.4e38f, -3.4e38f, -3.4e38f, -3.4e38f);
    float m0 = l4.x, m1 = l4.y, m2 = l4.z, m3 = l4.w;
#pragma unroll
    for (int off = 1; off < L; off <<= 1) {
      m0 = fmaxf(m0, __shfl_xor(m0, off));
      m1 = fmaxf(m1, __shfl_xor(m1, off));
      m2 = fmaxf(m2, __shfl_xor(m2, off));
      m3 = fmaxf(m3, __shfl_xor(m3, off));
    }
    float e0 = __expf(l4.x - m0), e1 = __expf(l4.y - m1);
    float e2 = __expf(l4.z - m2), e3 = __expf(l4.w - m3);
    float s0 = e0, s1 = e1, s2 = e2, s3 = e3;
#pragma unroll
    for (int off = 1; off < L; off <<= 1) {
      s0 += __shfl_xor(s0, off);
      s1 += __shfl_xor(s1, off);
      s2 += __shfl_xor(s2, off);
      s3 += __shfl_xor(s3, off);
    }
    wl[wid][g][li][0] = e0 / s0;
    wl[wid][g][li][1] = e1 / s1;
    wl[wid][g][li][2] = e2 / s2;
    wl[wid][g][li][3] = e3 / s3;
    pl[wid][g][li] = p << 8;

    int myh = li / (L / 4);
    float acc[C];
#pragma unroll
    for (int c = 0; c < C; ++c) acc[c] = 0.f;
    for (int e = 0; e < mydeg; ++e) {
      int off = pl[wid][g][e];
      float wgt = wl[wid][g][e][myh];
      const char* src = vb + off + li * (C * 2);
      unsigned u[C / 2];
      if constexpr (C == 8) {
        uint4 v = *(const uint4*)src;
        u[0] = v.x; u[1] = v.y; u[2] = v.z; u[3] = v.w;
      } else {
        uint2 v = *(const uint2*)src;
        u[0] = v.x; u[1] = v.y;
      }
#pragma unroll
      for (int j = 0; j < C / 2; ++j) {
        acc[2 * j] = fmaf(wgt, __uint_as_float(u[j] << 16), acc[2 * j]);
        acc[2 * j + 1] = fmaf(wgt, __uint_as_float(u[j] & 0xffff0000u), acc[2 * j + 1]);
      }
    }
    float q[C], gv[C], bv[C];
#pragma unroll
    for (int j = 0; j < C / 4; ++j) {
      float4 t = *(const float4*)(Qflat + li * C + j * 4);
      q[j * 4] = t.x; q[j * 4 + 1] = t.y; q[j * 4 + 2] = t.z; q[j * 4 + 3] = t.w;
      t = *(const float4*)(g0 + li * C + j * 4);
      gv[j * 4] = t.x; gv[j * 4 + 1] = t.y; gv[j * 4 + 2] = t.z; gv[j * 4 + 3] = t.w;
      t = *(const float4*)(be0 + li * C + j * 4);
      bv[j * 4] = t.x; bv[j * 4 + 1] = t.y; bv[j * 4 + 2] = t.z; bv[j * 4 + 3] = t.w;
    }
    float t1 = 0.f, t2 = 0.f;
#pragma unroll
    for (int c = 0; c < C; ++c) {
      float x = acc[c] + q[c];
      acc[c] = x;
      t1 += x;
      t2 += x * x;
    }
#pragma unroll
    for (int off = 1; off < L; off <<= 1) {
      t1 += __shfl_xor(t1, off);
      t2 += __shfl_xor(t2, off);
    }
    float mean = t1 * (1.f / 128.f);
    float var = t2 * (1.f / 128.f) - mean * mean;
    float rs = rsqrtf(var + 1e-5f);
    if (tval && fast) {
      float o[C];
#pragma unroll
      for (int c = 0; c < C; ++c) o[c] = (acc[c] - mean) * rs * gv[c] + bv[c];
      char* dst = (char*)xmidb + (size_t)tg * 256 + li * (C * 2);
      if constexpr (C == 8) {
        uint4 pk;
        pk.x = ((unsigned)f2bf(o[1]) << 16) | f2bf(o[0]);
        pk.y = ((unsigned)f2bf(o[3]) << 16) | f2bf(o[2]);
        pk.z = ((unsigned)f2bf(o[5]) << 16) | f2bf(o[4]);
        pk.w = ((unsigned)f2bf(o[7]) << 16) | f2bf(o[6]);
        *(uint4*)dst = pk;
      } else {
        uint2 pk;
        pk.x = ((unsigned)f2bf(o[1]) << 16) | f2bf(o[0]);
        pk.y = ((unsigned)f2bf(o[3]) << 16) | f2bf(o[2]);
        *(uint2*)dst = pk;
      }
    }
    return;
  }

  // overflow fallback: one target per wave, any degree
  int cnt = *ovfcnt;
  if (cnt > OVF_CAP) cnt = OVF_CAP;
  int head = lane >> 4;
  for (int idx = ((int)blockIdx.x - mainBlocks) * 4 + wid; idx < cnt; idx += 128) {
    int tg = ovf[idx];
    int2 sc = seg[tg];
    int base = sc.x, deg = sc.y;
    float m0 = -3.4e38f, m1 = -3.4e38f, m2 = -3.4e38f, m3 = -3.4e38f;
    for (int i = lane; i < deg; i += 64) {
      int p = pins[base + i];
      float4 l4 = *(const float4*)(lg + p * 4);
      m0 = fmaxf(m0, l4.x); m1 = fmaxf(m1, l4.y);
      m2 = fmaxf(m2, l4.z); m3 = fmaxf(m3, l4.w);
    }
#pragma unroll
    for (int off = 1; off < 64; off <<= 1) {
      m0 = fmaxf(m0, __shfl_xor(m0, off));
      m1 = fmaxf(m1, __shfl_xor(m1, off));
      m2 = fmaxf(m2, __shfl_xor(m2, off));
      m3 = fmaxf(m3, __shfl_xor(m3, off));
    }
    float s0 = 0.f, s1 = 0.f, s2 = 0.f, s3 = 0.f;
    for (int i = lane; i < deg; i += 64) {
      int p = pins[base + i];
      float4 l4 = *(const float4*)(lg + p * 4);
      s0 += __expf(l4.x - m0); s1 += __expf(l4.y - m1);
      s2 += __expf(l4.z - m2); s3 += __expf(l4.w - m3);
    }
#pragma unroll
    for (int off = 1; off < 64; off <<= 1) {
      s0 += __shfl_xor(s0, off);
      s1 += __shfl_xor(s1, off);
      s2 += __shfl_xor(s2, off);
      s3 += __shfl_xor(s3, off);
    }
    float mh = (head & 2) ? ((head & 1) ? m3 : m2) : ((head & 1) ? m1 : m0);
    float sh = (head & 2) ? ((head & 1) ? s3 : s2) : ((head & 1) ? s1 : s0);
    float rdh = (deg > 0) ? 1.f / sh : 0.f;
    float acc0 = 0.f, acc1 = 0.f;
    for (int e = 0; e < deg; ++e) {
      int p = pins[base + e];
      float w0 = __expf(lg[p * 4 + head] - mh) * rdh;
      unsigned int v = *(const unsigned int*)(vb + (p << 8) + lane * 4);
      acc0 = fmaf(w0, __uint_as_float(v << 16), acc0);
      acc1 = fmaf(w0, __uint_as_float(v & 0xffff0000u), acc1);
    }
    float2 q2 = ((const float2*)Qflat)[lane];
    float x0v = acc0 + q2.x;
    float x1v = acc1 + q2.y;
    float t1 = x0v + x1v, t2 = x0v * x0v + x1v * x1v;
#pragma unroll
    for (int off = 1; off < 64; off <<= 1) {
      t1 += __shfl_xor(t1, off);
      t2 += __shfl_xor(t2, off);
    }
    float mean = t1 * (1.f / 128.f);
    float var = t2 * (1.f / 128.f) - mean * mean;
    float rs = rsqrtf(var + 1e-5f);
    float2 gg = ((const float2*)g0)[lane];
    float2 bb = ((const float2*)be0)[lane];
    float o0 = (x0v - mean) * rs * gg.x + bb.x;
    float o1 = (x1v - mean) * rs * gg.y + bb.y;
    unsigned int pk = ((unsigned int)f2bf(o1) << 16) | f2bf(o0);
    ((unsigned int*)xmidb)[tg * 64 + lane] = pk;
  }
}

// ---------------------------------------------------------------------------
// mlp128: register-blocked mlp (+optional fused transform). 128 rows/block,
// 4 waves x 2 row-groups x 16 rows. Each B-frag ds_read feeds 2 MFMAs
// (GEMM phases were LDS-read-bound: ds_read_b128 ~12cyc vs MFMA ~5cyc).
// LDS (64KB): Wlds [0,32K) (W1 -> W2 -> Blds tiles 0-7); HX [32K,64K)
// (Hlds -> Xout -> Olds; per-wave-private rows make aliasing safe — same-wave
// DS ops are in-order). Transform's 9th B-tile (logits) read from L2 global.
// ---------------------------------------------------------------------------
__global__ __launch_bounds__(256) void mlp128(
    const ushort_t* __restrict__ xmb, const ushort_t* __restrict__ W1sw,
    const float* __restrict__ b1, const ushort_t* __restrict__ W2sw,
    const float* __restrict__ b2, const float* __restrict__ g1,
    const float* __restrict__ be1, float* __restrict__ outf, int n, int wf32,
    const ushort_t* __restrict__ Bsw, ushort_t* __restrict__ Vxb,
    float* __restrict__ lg) {
  __shared__ char S[65536];
  char* Wlds = S;
  char* HX = S + 32768;
  int t = threadIdx.x, l = t & 63, w = t >> 6;
  size_t r0 = (size_t)blockIdx.x * 128;
  int rb = w * 32;                 // wave row base (local)
  int swz = (l & 7) << 4;
  int lbase = (l & 15) * 256 + (l >> 4) * 16;
  bool do_tf = (Bsw != nullptr);

#pragma unroll
  for (int it = 0; it < 8; ++it) {
    int off = it * 4096 + w * 1024 + l * 16;
    gload16((const char*)W1sw + off, Wlds + off);
  }
  float b1v[8], b2v[8], g1v[8], be1v[8];
#pragma unroll
  for (int ct = 0; ct < 8; ++ct) {
    int c = ct * 16 + (l & 15);
    b1v[ct] = b1[c]; b2v[ct] = b2[c]; g1v[ct] = g1[c]; be1v[ct] = be1[c];
  }
  __syncthreads();

  // ---- GEMM1: h = relu(x@W1+b1), 2 row-groups per wave ----
  f32x4 acc0[8], acc1[8];
#pragma unroll
  for (int ct = 0; ct < 8; ++ct) {
    acc0[ct] = (f32x4){b1v[ct], b1v[ct], b1v[ct], b1v[ct]};
    acc1[ct] = (f32x4){b1v[ct], b1v[ct], b1v[ct], b1v[ct]};
  }
  const ushort_t* a0p = xmb + (r0 + rb + (l & 15)) * 128 + (l >> 4) * 8;
  const ushort_t* a1p = a0p + 16 * 128;
#pragma unroll
  for (int kk = 0; kk < 4; ++kk) {
    bf16x8 a0 = *(const bf16x8*)(a0p + kk * 32);
    bf16x8 a1 = *(const bf16x8*)(a1p + kk * 32);
#pragma unroll
    for (int ct = 0; ct < 8; ++ct) {
      bf16x8 b = *(const bf16x8*)(Wlds + ((ct * 4096 + kk * 64 + lbase) ^ swz));
      acc0[ct] = __builtin_amdgcn_mfma_f32_16x16x32_bf16(a0, b, acc0[ct], 0, 0, 0);
      acc1[ct] = __builtin_amdgcn_mfma_f32_16x16x32_bf16(a1, b, acc1[ct], 0, 0, 0);
    }
  }
  // h1 -> HX (swizzled rows; per-wave-private)
#pragma unroll
  for (int ct = 0; ct < 8; ++ct) {
    int c2 = (ct * 16 + (l & 15)) * 2;
#pragma unroll
    for (int j = 0; j < 4; ++j) {
      int rl0 = rb + (l >> 4) * 4 + j;
      int rl1 = rl0 + 16;
      *(ushort_t*)(HX + ((rl0 * 256 + c2) ^ ((rl0 & 7) << 4))) = f2bf(fmaxf(acc0[ct][j], 0.f));
      *(ushort_t*)(HX + ((rl1 * 256 + c2) ^ ((rl1 & 7) << 4))) = f2bf(fmaxf(acc1[ct][j], 0.f));
    }
  }
  __syncthreads();  // W1 reads done everywhere
#pragma unroll
  for (int it = 0; it < 8; ++it) {
    int off = it * 4096 + w * 1024 + l * 16;
    gload16((const char*)W2sw + off, Wlds + off);
  }
  __syncthreads();  // W2 staged (+ h writes visible)

  // ---- GEMM2: y = h@W2+b2 ----
  f32x4 ac20[8], ac21[8];
#pragma unroll
  for (int ct = 0; ct < 8; ++ct) {
    ac20[ct] = (f32x4){b2v[ct], b2v[ct], b2v[ct], b2v[ct]};
    ac21[ct] = (f32x4){b2v[ct], b2v[ct], b2v[ct], b2v[ct]};
  }
  int h0base = (rb + (l & 15)) * 256;
  int h1base = h0base + 16 * 256;
#pragma unroll
  for (int kk = 0; kk < 4; ++kk) {
    bf16x8 a0 = *(const bf16x8*)(HX + h0base + (((l >> 4) * 16 + kk * 64) ^ swz));
    bf16x8 a1 = *(const bf16x8*)(HX + h1base + (((l >> 4) * 16 + kk * 64) ^ swz));
#pragma unroll
    for (int ct = 0; ct < 8; ++ct) {
      bf16x8 b = *(const bf16x8*)(Wlds + ((ct * 4096 + kk * 64 + lbase) ^ swz));
      ac20[ct] = __builtin_amdgcn_mfma_f32_16x16x32_bf16(a0, b, ac20[ct], 0, 0, 0);
      ac21[ct] = __builtin_amdgcn_mfma_f32_16x16x32_bf16(a1, b, ac21[ct], 0, 0, 0);
    }
  }
  // ---- residual + LN1 + relu, per row-group ----
  size_t rbase0 = r0 + rb + (l >> 4) * 4;
  size_t rbase1 = rbase0 + 16;
  float s10[4] = {0, 0, 0, 0}, s20[4] = {0, 0, 0, 0};
  float s11[4] = {0, 0, 0, 0}, s21[4] = {0, 0, 0, 0};
#pragma unroll
  for (int ct = 0; ct < 8; ++ct) {
    int c = ct * 16 + (l & 15);
#pragma unroll
    for (int j = 0; j < 4; ++j) {
      float x0 = bf2f(xmb[(rbase0 + j) * 128 + c]);
      float y0 = ac20[ct][j] + x0;
      ac20[ct][j] = y0; s10[j] += y0; s20[j] += y0 * y0;
      float x1 = bf2f(xmb[(rbase1 + j) * 128 + c]);
      float y1 = ac21[ct][j] + x1;
      ac21[ct][j] = y1; s11[j] += y1; s21[j] += y1 * y1;
    }
  }
#pragma unroll
  for (int off = 1; off < 16; off <<= 1) {
#pragma unroll
    for (int j = 0; j < 4; ++j) {
      s10[j] += __shfl_xor(s10[j], off);
      s20[j] += __shfl_xor(s20[j], off);
      s11[j] += __shfl_xor(s11[j], off);
      s21[j] += __shfl_xor(s21[j], off);
    }
  }
  float mean0[4], rs0[4], mean1[4], rs1[4];
#pragma unroll
  for (int j = 0; j < 4; ++j) {
    mean0[j] = s10[j] * (1.f / 128.f);
    rs0[j] = rsqrtf(s20[j] * (1.f / 128.f) - mean0[j] * mean0[j] + 1e-5f);
    mean1[j] = s11[j] * (1.f / 128.f);
    rs1[j] = rsqrtf(s21[j] * (1.f / 128.f) - mean1[j] * mean1[j] + 1e-5f);
  }
  // write outputs: f32 (optional) + Xout over HX (per-wave-private rows;
  // same-wave DS in-order so reads-before-writes within wave are safe)
#pragma unroll
  for (int ct = 0; ct < 8; ++ct) {
    int c = ct * 16 + (l & 15);
    int c2 = c * 2;
#pragma unroll
    for (int j = 0; j < 4; ++j) {
      float o0 = fmaxf((ac20[ct][j] - mean0[j]) * rs0[j] * g1v[ct] + be1v[ct], 0.f);
      float o1 = fmaxf((ac21[ct][j] - mean1[j]) * rs1[j] * g1v[ct] + be1v[ct], 0.f);
      int rl0 = rb + (l >> 4) * 4 + j;
      int rl1 = rl0 + 16;
      if (do_tf) {
        *(ushort_t*)(HX + ((rl0 * 256 + c2) ^ ((rl0 & 7) << 4))) = f2bf(o0);
        *(ushort_t*)(HX + ((rl1 * 256 + c2) ^ ((rl1 & 7) << 4))) = f2bf(o1);
      }
      if (wf32) {
        size_t row0 = rbase0 + j, row1 = rbase1 + j;
        if (row0 < (size_t)n) outf[row0 * 128 + c] = o0;
        if (row1 < (size_t)n) outf[row1 * 128 + c] = o1;
      }
    }
  }
  if (!do_tf) return;
  __syncthreads();  // Xout complete; W2 reads done -> Wlds reusable

  // ---- fused transform of next block: A = Xout, B tiles 0-7 from LDS,
  //      tile 8 (logits) from L2-hot global ----
  char* Blds = S;  // 8 tiles = exactly 32KB over dead Wlds
#pragma unroll
  for (int it = 0; it < 8; ++it) {
    int off = it * 4096 + w * 1024 + l * 16;
    gload16((const char*)Bsw + off, Blds + off);
  }
  __syncthreads();

  f32x4 ta0[9], ta1[9];
#pragma unroll
  for (int ct = 0; ct < 9; ++ct) {
    ta0[ct] = (f32x4){0.f, 0.f, 0.f, 0.f};
    ta1[ct] = (f32x4){0.f, 0.f, 0.f, 0.f};
  }
#pragma unroll
  for (int kk = 0; kk < 4; ++kk) {
    bf16x8 a0 = *(const bf16x8*)(HX + h0base + (((l >> 4) * 16 + kk * 64) ^ swz));
    bf16x8 a1 = *(const bf16x8*)(HX + h1base + (((l >> 4) * 16 + kk * 64) ^ swz));
#pragma unroll
    for (int ct = 0; ct < 8; ++ct) {
      bf16x8 b = *(const bf16x8*)(Blds + ((ct * 4096 + kk * 64 + lbase) ^ swz));
      ta0[ct] = __builtin_amdgcn_mfma_f32_16x16x32_bf16(a0, b, ta0[ct], 0, 0, 0);
      ta1[ct] = __builtin_amdgcn_mfma_f32_16x16x32_bf16(a1, b, ta1[ct], 0, 0, 0);
    }
    bf16x8 bq = *(const bf16x8*)((const char*)Bsw + 32768 + ((kk * 64 + lbase) ^ swz));
    ta0[8] = __builtin_amdgcn_mfma_f32_16x16x32_bf16(a0, bq, ta0[8], 0, 0, 0);
    ta1[8] = __builtin_amdgcn_mfma_f32_16x16x32_bf16(a1, bq, ta1[8], 0, 0, 0);
  }
  if ((l & 15) < 4) {
#pragma unroll
    for (int j = 0; j < 4; ++j) {
      lg[(rbase0 + j) * 4 + (l & 15)] = ta0[8][j];
      lg[(rbase1 + j) * 4 + (l & 15)] = ta1[8][j];
    }
  }
  __syncthreads();  // Xout A-reads done -> HX reusable as Olds
  char* Olds = HX;
#pragma unroll
  for (int ct = 0; ct < 8; ++ct) {
    int c2 = (ct * 16 + (l & 15)) * 2;
#pragma unroll
    for (int j = 0; j < 4; ++j) {
      int rr0 = rb + (l >> 4) * 4 + j;
      int rr1 = rr0 + 16;
      *(ushort_t*)(Olds + ((rr0 * 256 + c2) ^ ((rr0 & 0xC) << 3))) = f2bf(ta0[ct][j]);
      *(ushort_t*)(Olds + ((rr1 * 256 + c2) ^ ((rr1 & 0xC) << 3))) = f2bf(ta1[ct][j]);
    }
  }
  __syncthreads();
#pragma unroll
  for (int it = 0; it < 8; ++it) {
    int L = it * 4096 + t * 16;
    int r = L >> 8;
    int phys = L ^ ((r & 0xC) << 3);
    *(uint4*)((char*)Vxb + r0 * 256 + L) = *(const uint4*)(Olds + phys);
  }
}

// ---------------------------------------------------------------------------
extern "C" void kernel_launch(void* const* d_in, const int* in_sizes, int n_in,
                              void* d_out, int out_size, void* d_ws, size_t ws_size,
                              hipStream_t stream) {
  const float* x0_in = (const float*)d_in[0];
  const float* Kw  = (const float*)d_in[1];
  const float* Vw  = (const float*)d_in[2];
  const float* Qw  = (const float*)d_in[3];
  const float* W1  = (const float*)d_in[4];
  const float* b1  = (const float*)d_in[5];
  const float* W2  = (const float*)d_in[6];
  const float* b2  = (const float*)d_in[7];
  const float* ln0g = (const float*)d_in[8];
  const float* ln0b = (const float*)d_in[9];
  const float* ln1g = (const float*)d_in[10];
  const float* ln1b = (const float*)d_in[11];
  const int* node_idx  = (const int*)d_in[12];
  const int* hedge_idx = (const int*)d_in[13];

  float* out = (float*)d_out;
  float* x0_out = out;
  float* x1_out = out + (size_t)N_NODES * 128;

  char* w = (char*)d_ws;
  auto alloc = [&](size_t bytes) -> void* {
    void* p = (void*)w;
    w += (bytes + 255) & ~(size_t)255;
    return p;
  };
  ushort_t* Vvqsw = (ushort_t*)alloc(4 * 18432 * 2);
  ushort_t* W1sw  = (ushort_t*)alloc(4 * 16384 * 2);
  ushort_t* W2sw  = (ushort_t*)alloc(4 * 16384 * 2);
  ushort_t* x0b   = (ushort_t*)alloc((size_t)NPN * 128 * 2);
  ushort_t* Vxb   = (ushort_t*)alloc((size_t)NPN * 128 * 2);
  float*    lg    = (float*)alloc((size_t)NPN * 4 * 4);
  ushort_t* xmidb = (ushort_t*)alloc((size_t)NPN * 128 * 2);
  int2* segH  = (int2*)alloc((size_t)N_HEDGES * 8);
  int2* segN  = (int2*)alloc((size_t)N_NODES * 8);
  int* pinsH  = (int*)alloc(N_PINS * 4);
  int* pinsN  = (int*)alloc(N_PINS * 4);
  int* ovfH   = (int*)alloc(OVF_CAP * 4);
  int* ovfN   = (int*)alloc(OVF_CAP * 4);
  unsigned* rank2 = (unsigned*)alloc((size_t)N_PINS * 4);
  int* zbase  = (int*)alloc((size_t)(N_HEDGES + N_NODES + 4) * 4);
  int* cntH = zbase;
  int* cntN = cntH + N_HEDGES;
  int* gctr = cntN + N_NODES;  // [gH, gN, ovfcntH, ovfcntN]

  hipMemsetAsync(zbase, 0, (size_t)(N_HEDGES + N_NODES + 4) * 4, stream);

  fused_front<<<2048, 256, 0, stream>>>(x0_in, x0b, node_idx, hedge_idx, cntN, cntH,
                                        rank2, Kw, Vw, Qw, W1, W2, Vvqsw, W1sw, W2sw);
  scan_tf<<<SCAN_B + TB, 256, 0, stream>>>(cntH, segH, ovfH, cntN, segN, ovfN,
                                           gctr, x0b, Vvqsw, Vxb, lg);
  csr_fill<<<(N_PINS + 255) / 256, 256, 0, stream>>>(node_idx, hedge_idx, rank2,
                                                     segN, segH, pinsN, pinsH);

  const int2* segs[4] = {segH, segN, segH, segN};
  const int* pinss[4] = {pinsH, pinsN, pinsH, pinsN};
  int n_tgts[4] = {N_HEDGES, N_NODES, N_HEDGES, N_NODES};
  const int mbH = (N_HEDGES + 7) / 8;     // L=32: 8 targets/block
  const int mbN = (N_NODES + 15) / 16;    // L=16: 16 targets/block

  for (int b = 0; b < 4; ++b) {
    int n_tgt = n_tgts[b];
    if (b & 1) {
      attn_g<16><<<mbN + 32, 256, 0, stream>>>(Vxb, lg, segs[b], pinss[b],
                                               Qw + b * 128, ln0g + b * 128,
                                               ln0b + b * 128, xmidb, n_tgt,
                                               mbN, ovfN, gctr + 3);
    } else {
      attn_g<32><<<mbH + 32, 256, 0, stream>>>(Vxb, lg, segs[b], pinss[b],
                                               Qw + b * 128, ln0g + b * 128,
                                               ln0b + b * 128, xmidb, n_tgt,
                                               mbH, ovfH, gctr + 2);
    }
    int nblk = (n_tgt + 127) / 128;
    if (b < 3) {
      int wf32 = (b == 2) ? 1 : 0;
      float* of = (b == 2) ? x1_out : nullptr;
      mlp128<<<nblk, 256, 0, stream>>>(
          xmidb, W1sw + b * 16384, b1 + b * 128, W2sw + b * 16384, b2 + b * 128,
          ln1g + b * 128, ln1b + b * 128, of, n_tgt, wf32,
          Vvqsw + (b + 1) * 18432, Vxb, lg);
    } else {
      mlp128<<<nblk, 256, 0, stream>>>(
          xmidb, W1sw + b * 16384, b1 + b * 128, W2sw + b * 16384, b2 + b * 128,
          ln1g + b * 128, ln1b + b * 128, x0_out, n_tgt, 1,
          nullptr, nullptr, nullptr);
    }
  }
}

// Round 14
// 266.380 us; speedup vs baseline: 1.1501x; 1.1501x over previous
//
#include <hip/hip_runtime.h>

#define N_NODES 100000
#define N_HEDGES 30000
#define N_PINS 400000
#define NPN 100096   // padded node rows
#define OVF_CAP 8192
#define SCAN_BH 118  // ceil(30000/256)
#define SCAN_BN 391  // ceil(100000/256)
#define SCAN_B (SCAN_BH + SCAN_BN)
#define TB 1563      // transform blocks = ceil(100000/64)

typedef __attribute__((ext_vector_type(8))) short bf16x8;
typedef __attribute__((ext_vector_type(4))) float f32x4;
typedef unsigned short ushort_t;

__device__ __forceinline__ unsigned short f2bf(float f) {
  unsigned int u = __float_as_uint(f);
  u += 0x7FFF + ((u >> 16) & 1);
  return (unsigned short)(u >> 16);
}
__device__ __forceinline__ float bf2f(unsigned short s) {
  return __uint_as_float(((unsigned int)s) << 16);
}
__device__ __forceinline__ void gload16(const void* g, void* l) {
  __builtin_amdgcn_global_load_lds(
      (const __attribute__((address_space(1))) unsigned int*)g,
      (__attribute__((address_space(3))) unsigned int*)l, 16, 0, 0);
}

// ---------------------------------------------------------------------------
// fused front-end (proven): atomics issued first, rank2 written last;
// vectorized conv; weight prep. Atomic-throughput-bound (~47us floor).
// ---------------------------------------------------------------------------
__global__ __launch_bounds__(256) void fused_front(
    const float* __restrict__ x0_in, ushort_t* __restrict__ x0b,
    const int* __restrict__ node_idx, const int* __restrict__ hedge_idx,
    int* __restrict__ cntN, int* __restrict__ cntH, unsigned* __restrict__ rank2,
    const float* __restrict__ Kw, const float* __restrict__ Vw,
    const float* __restrict__ Qw, const float* __restrict__ W1,
    const float* __restrict__ W2, ushort_t* __restrict__ Vvqsw,
    ushort_t* __restrict__ W1sw, ushort_t* __restrict__ W2sw) {
  int gsz = gridDim.x * 256;
  int tid = blockIdx.x * 256 + threadIdx.x;
  int rn = 0, rh = 0;
  bool hasPin = tid < N_PINS;
  if (hasPin) {
    int n_i = node_idx[tid], h_i = hedge_idx[tid];
    rn = atomicAdd(&cntN[n_i], 1);
    rh = atomicAdd(&cntH[h_i], 1);
  }
  for (int i = tid; i < N_NODES * 16; i += gsz) {
    const float4* s = (const float4*)x0_in + (size_t)i * 2;
    float4 a = s[0], b = s[1];
    uint4 o;
    o.x = ((unsigned)f2bf(a.y) << 16) | f2bf(a.x);
    o.y = ((unsigned)f2bf(a.w) << 16) | f2bf(a.z);
    o.z = ((unsigned)f2bf(b.y) << 16) | f2bf(b.x);
    o.w = ((unsigned)f2bf(b.w) << 16) | f2bf(b.z);
    ((uint4*)x0b)[i] = o;
  }
  for (int i = tid; i < 4 * 144 * 128; i += gsz) {
    int b = i / 18432, r = i % 18432, c = r >> 7, d = r & 127;
    float v;
    if (c < 128) {
      v = Vw[((b * 4 + (c >> 5)) * 128 + d) * 32 + (c & 31)];
    } else if (c < 132) {
      int h = c - 128;
      const float* kp = Kw + ((b * 4 + h) * 128 + d) * 32;
      const float* qp = Qw + (b * 4 + h) * 32;
      float s = 0.f;
      for (int k = 0; k < 32; ++k) s += kp[k] * qp[k];
      v = s;
    } else {
      v = 0.f;
    }
    int L = (c * 256 + d * 2) ^ ((c & 7) << 4);
    Vvqsw[b * 18432 + L / 2] = f2bf(v);
  }
  for (int i = tid; i < 4 * 128 * 128; i += gsz) {
    int b = i >> 14, r = i & 16383, c = r >> 7, k = r & 127;
    int L = (c * 256 + k * 2) ^ ((c & 7) << 4);
    int idx = b * 16384 + L / 2;
    W1sw[idx] = f2bf(W1[b * 16384 + k * 128 + c]);
    W2sw[idx] = f2bf(W2[b * 16384 + k * 128 + c]);
  }
  if (hasPin) rank2[tid] = ((unsigned)rh << 16) | (unsigned)rn;
}

// ---------------------------------------------------------------------------
// scan_tf (proven round 12): merged scan + transform(b0).
// ---------------------------------------------------------------------------
__global__ __launch_bounds__(256) void scan_tf(
    const int* __restrict__ cntH, int2* __restrict__ segH, int* __restrict__ ovfH,
    const int* __restrict__ cntN, int2* __restrict__ segN, int* __restrict__ ovfN,
    int* __restrict__ gctr, const ushort_t* __restrict__ xb,
    const ushort_t* __restrict__ Bsw, ushort_t* __restrict__ Vxb,
    float* __restrict__ lg) {
  __shared__ char Blds[36864];
  __shared__ char Olds[16384];
  __shared__ int wsum[4];
  __shared__ int bbase;
  int t = threadIdx.x, l = t & 63, w = t >> 6;

  if ((int)blockIdx.x < SCAN_B) {
    bool isH = (int)blockIdx.x < SCAN_BH;
    const int* cnt = isH ? cntH : cntN;
    int2* seg = isH ? segH : segN;
    int* ovf = isH ? ovfH : ovfN;
    int* g = gctr + (isH ? 0 : 1);
    int* oc = gctr + (isH ? 2 : 3);
    int thresh = isH ? 32 : 16;
    int n = isH ? N_HEDGES : N_NODES;
    int i = (isH ? (int)blockIdx.x : (int)blockIdx.x - SCAN_BH) * 256 + t;
    int lane = t & 63, wid = t >> 6;
    int v = (i < n) ? cnt[i] : 0;
    int sc = v;
#pragma unroll
    for (int s = 1; s < 64; s <<= 1) {
      int tv = __shfl_up(sc, s);
      if (lane >= s) sc += tv;
    }
    if (lane == 63) wsum[wid] = sc;
    __syncthreads();
    if (t == 0) {
      int s0 = wsum[0], s1 = wsum[1], s2 = wsum[2], s3 = wsum[3];
      wsum[0] = 0; wsum[1] = s0; wsum[2] = s0 + s1; wsum[3] = s0 + s1 + s2;
      bbase = atomicAdd(g, s0 + s1 + s2 + s3);
    }
    __syncthreads();
    if (i < n) {
      int st = bbase + wsum[wid] + (sc - v);
      seg[i] = make_int2(st, v);
      if (v > thresh) {
        int k = atomicAdd(oc, 1);
        if (k < OVF_CAP) ovf[k] = i;
      }
    }
    return;
  }

  size_t r0 = (size_t)((int)blockIdx.x - SCAN_B) * 64;
#pragma unroll
  for (int it = 0; it < 9; ++it) {
    int off = it * 4096 + w * 1024 + l * 16;
    gload16((const char*)Bsw + off, Blds + off);
  }
  __syncthreads();

  f32x4 acc[9];
#pragma unroll
  for (int ct = 0; ct < 9; ++ct) acc[ct] = (f32x4){0.f, 0.f, 0.f, 0.f};
  int swz = (l & 7) << 4;
  int lbase = (l & 15) * 256 + (l >> 4) * 16;
  const ushort_t* abase = xb + (r0 + w * 16 + (l & 15)) * 128 + (l >> 4) * 8;
#pragma unroll
  for (int kk = 0; kk < 4; ++kk) {
    bf16x8 a = *(const bf16x8*)(abase + kk * 32);
#pragma unroll
    for (int ct = 0; ct < 9; ++ct) {
      bf16x8 b = *(const bf16x8*)(Blds + ((ct * 4096 + kk * 64 + lbase) ^ swz));
      acc[ct] = __builtin_amdgcn_mfma_f32_16x16x32_bf16(a, b, acc[ct], 0, 0, 0);
    }
  }
  if ((l & 15) < 4) {
    size_t rb = r0 + w * 16 + (l >> 4) * 4;
#pragma unroll
    for (int j = 0; j < 4; ++j) lg[(rb + j) * 4 + (l & 15)] = acc[8][j];
  }
  int row64 = w * 16 + (l >> 4) * 4;
#pragma unroll
  for (int ct = 0; ct < 8; ++ct) {
    int c2 = (ct * 16 + (l & 15)) * 2;
#pragma unroll
    for (int j = 0; j < 4; ++j) {
      int r = row64 + j;
      int addr = (r * 256 + c2) ^ ((r & 0xC) << 3);
      *(ushort_t*)(Olds + addr) = f2bf(acc[ct][j]);
    }
  }
  __syncthreads();
#pragma unroll
  for (int it = 0; it < 4; ++it) {
    int L = it * 4096 + t * 16;
    int r = L >> 8;
    int phys = L ^ ((r & 0xC) << 3);
    *(uint4*)((char*)Vxb + r0 * 256 + L) = *(const uint4*)(Olds + phys);
  }
}

// ---------------------------------------------------------------------------
// fill, atomic-free (proven)
// ---------------------------------------------------------------------------
__global__ __launch_bounds__(256) void csr_fill(
    const int* __restrict__ node_idx, const int* __restrict__ hedge_idx,
    const unsigned* __restrict__ rank2, const int2* __restrict__ segN,
    const int2* __restrict__ segH, int* __restrict__ pinsN,
    int* __restrict__ pinsH) {
  int e = blockIdx.x * 256 + threadIdx.x;
  if (e < N_PINS) {
    int n = node_idx[e], h = hedge_idx[e];
    unsigned r2 = rank2[e];
    pinsH[segH[h].x + (int)(r2 >> 16)] = n;
    pinsN[segN[n].x + (int)(r2 & 0xffffu)] = h;
  }
}

// ---------------------------------------------------------------------------
// attention (proven round-10): grouped, L lanes/target, one-shot softmax
// for deg<=L, overflow fallback for deg>L. L=16 nodes / L=32 hedges.
// ---------------------------------------------------------------------------
template <int L>
__global__ __launch_bounds__(256) void attn_g(
    const ushort_t* __restrict__ Vxb, const float* __restrict__ lg,
    const int2* __restrict__ seg, const int* __restrict__ pins,
    const float* __restrict__ Qflat, const float* __restrict__ g0,
    const float* __restrict__ be0, ushort_t* __restrict__ xmidb, int n_tgt,
    int mainBlocks, const int* __restrict__ ovf, const int* __restrict__ ovfcnt) {
  constexpr int G = 64 / L;
  constexpr int C = 128 / L;
  __shared__ float wl[4][G][L][4];
  __shared__ int pl[4][G][L];
  int wid = threadIdx.x >> 6, lane = threadIdx.x & 63;
  const char* vb = (const char*)Vxb;

  if ((int)blockIdx.x < mainBlocks) {
    int g = lane / L, li = lane % L;
    int tg = ((int)blockIdx.x * 4 + wid) * G + g;
    bool tval = tg < n_tgt;
    int2 sc = tval ? seg[tg] : make_int2(0, 0);
    int base = sc.x, deg = sc.y;
    bool fast = deg <= L;
    int mydeg = (tval && fast) ? deg : 0;
    bool act = li < mydeg;
    int p = act ? pins[base + li] : 0;
    float4 l4;
    if (act) l4 = *(const float4*)(lg + p * 4);
    else l4 = make_float4(-3.4e38f, -3.4e38f, -3.4e38f, -3.4e38f);
    float m0 = l4.x, m1 = l4.y, m2 = l4.z, m3 = l4.w;
#pragma unroll
    for (int off = 1; off < L; off <<= 1) {
      m0 = fmaxf(m0, __shfl_xor(m0, off));
      m1 = fmaxf(m1, __shfl_xor(m1, off));
      m2 = fmaxf(m2, __shfl_xor(m2, off));
      m3 = fmaxf(m3, __shfl_xor(m3, off));
    }
    float e0 = __expf(l4.x - m0), e1 = __expf(l4.y - m1);
    float e2 = __expf(l4.z - m2), e3 = __expf(l4.w - m3);
    float s0 = e0, s1 = e1, s2 = e2, s3 = e3;
#pragma unroll
    for (int off = 1; off < L; off <<= 1) {
      s0 += __shfl_xor(s0, off);
      s1 += __shfl_xor(s1, off);
      s2 += __shfl_xor(s2, off);
      s3 += __shfl_xor(s3, off);
    }
    wl[wid][g][li][0] = e0 / s0;
    wl[wid][g][li][1] = e1 / s1;
    wl[wid][g][li][2] = e2 / s2;
    wl[wid][g][li][3] = e3 / s3;
    pl[wid][g][li] = p << 8;

    int myh = li / (L / 4);
    float acc[C];
#pragma unroll
    for (int c = 0; c < C; ++c) acc[c] = 0.f;
    for (int e = 0; e < mydeg; ++e) {
      int off = pl[wid][g][e];
      float wgt = wl[wid][g][e][myh];
      const char* src = vb + off + li * (C * 2);
      unsigned u[C / 2];
      if constexpr (C == 8) {
        uint4 v = *(const uint4*)src;
        u[0] = v.x; u[1] = v.y; u[2] = v.z; u[3] = v.w;
      } else {
        uint2 v = *(const uint2*)src;
        u[0] = v.x; u[1] = v.y;
      }
#pragma unroll
      for (int j = 0; j < C / 2; ++j) {
        acc[2 * j] = fmaf(wgt, __uint_as_float(u[j] << 16), acc[2 * j]);
        acc[2 * j + 1] = fmaf(wgt, __uint_as_float(u[j] & 0xffff0000u), acc[2 * j + 1]);
      }
    }
    float q[C], gv[C], bv[C];
#pragma unroll
    for (int j = 0; j < C / 4; ++j) {
      float4 t = *(const float4*)(Qflat + li * C + j * 4);
      q[j * 4] = t.x; q[j * 4 + 1] = t.y; q[j * 4 + 2] = t.z; q[j * 4 + 3] = t.w;
      t = *(const float4*)(g0 + li * C + j * 4);
      gv[j * 4] = t.x; gv[j * 4 + 1] = t.y; gv[j * 4 + 2] = t.z; gv[j * 4 + 3] = t.w;
      t = *(const float4*)(be0 + li * C + j * 4);
      bv[j * 4] = t.x; bv[j * 4 + 1] = t.y; bv[j * 4 + 2] = t.z; bv[j * 4 + 3] = t.w;
    }
    float t1 = 0.f, t2 = 0.f;
#pragma unroll
    for (int c = 0; c < C; ++c) {
      float x = acc[c] + q[c];
      acc[c] = x;
      t1 += x;
      t2 += x * x;
    }
#pragma unroll
    for (int off = 1; off < L; off <<= 1) {
      t1 += __shfl_xor(t1, off);
      t2 += __shfl_xor(t2, off);
    }
    float mean = t1 * (1.f / 128.f);
    float var = t2 * (1.f / 128.f) - mean * mean;
    float rs = rsqrtf(var + 1e-5f);
    if (tval && fast) {
      float o[C];
#pragma unroll
      for (int c = 0; c < C; ++c) o[c] = (acc[c] - mean) * rs * gv[c] + bv[c];
      char* dst = (char*)xmidb + (size_t)tg * 256 + li * (C * 2);
      if constexpr (C == 8) {
        uint4 pk;
        pk.x = ((unsigned)f2bf(o[1]) << 16) | f2bf(o[0]);
        pk.y = ((unsigned)f2bf(o[3]) << 16) | f2bf(o[2]);
        pk.z = ((unsigned)f2bf(o[5]) << 16) | f2bf(o[4]);
        pk.w = ((unsigned)f2bf(o[7]) << 16) | f2bf(o[6]);
        *(uint4*)dst = pk;
      } else {
        uint2 pk;
        pk.x = ((unsigned)f2bf(o[1]) << 16) | f2bf(o[0]);
        pk.y = ((unsigned)f2bf(o[3]) << 16) | f2bf(o[2]);
        *(uint2*)dst = pk;
      }
    }
    return;
  }

  // overflow fallback: one target per wave, any degree
  int cnt = *ovfcnt;
  if (cnt > OVF_CAP) cnt = OVF_CAP;
  int head = lane >> 4;
  for (int idx = ((int)blockIdx.x - mainBlocks) * 4 + wid; idx < cnt; idx += 128) {
    int tg = ovf[idx];
    int2 sc = seg[tg];
    int base = sc.x, deg = sc.y;
    float m0 = -3.4e38f, m1 = -3.4e38f, m2 = -3.4e38f, m3 = -3.4e38f;
    for (int i = lane; i < deg; i += 64) {
      int p = pins[base + i];
      float4 l4 = *(const float4*)(lg + p * 4);
      m0 = fmaxf(m0, l4.x); m1 = fmaxf(m1, l4.y);
      m2 = fmaxf(m2, l4.z); m3 = fmaxf(m3, l4.w);
    }
#pragma unroll
    for (int off = 1; off < 64; off <<= 1) {
      m0 = fmaxf(m0, __shfl_xor(m0, off));
      m1 = fmaxf(m1, __shfl_xor(m1, off));
      m2 = fmaxf(m2, __shfl_xor(m2, off));
      m3 = fmaxf(m3, __shfl_xor(m3, off));
    }
    float s0 = 0.f, s1 = 0.f, s2 = 0.f, s3 = 0.f;
    for (int i = lane; i < deg; i += 64) {
      int p = pins[base + i];
      float4 l4 = *(const float4*)(lg + p * 4);
      s0 += __expf(l4.x - m0); s1 += __expf(l4.y - m1);
      s2 += __expf(l4.z - m2); s3 += __expf(l4.w - m3);
    }
#pragma unroll
    for (int off = 1; off < 64; off <<= 1) {
      s0 += __shfl_xor(s0, off);
      s1 += __shfl_xor(s1, off);
      s2 += __shfl_xor(s2, off);
      s3 += __shfl_xor(s3, off);
    }
    float mh = (head & 2) ? ((head & 1) ? m3 : m2) : ((head & 1) ? m1 : m0);
    float sh = (head & 2) ? ((head & 1) ? s3 : s2) : ((head & 1) ? s1 : s0);
    float rdh = (deg > 0) ? 1.f / sh : 0.f;
    float acc0 = 0.f, acc1 = 0.f;
    for (int e = 0; e < deg; ++e) {
      int p = pins[base + e];
      float w0 = __expf(lg[p * 4 + head] - mh) * rdh;
      unsigned int v = *(const unsigned int*)(vb + (p << 8) + lane * 4);
      acc0 = fmaf(w0, __uint_as_float(v << 16), acc0);
      acc1 = fmaf(w0, __uint_as_float(v & 0xffff0000u), acc1);
    }
    float2 q2 = ((const float2*)Qflat)[lane];
    float x0v = acc0 + q2.x;
    float x1v = acc1 + q2.y;
    float t1 = x0v + x1v, t2 = x0v * x0v + x1v * x1v;
#pragma unroll
    for (int off = 1; off < 64; off <<= 1) {
      t1 += __shfl_xor(t1, off);
      t2 += __shfl_xor(t2, off);
    }
    float mean = t1 * (1.f / 128.f);
    float var = t2 * (1.f / 128.f) - mean * mean;
    float rs = rsqrtf(var + 1e-5f);
    float2 gg = ((const float2*)g0)[lane];
    float2 bb = ((const float2*)be0)[lane];
    float o0 = (x0v - mean) * rs * gg.x + bb.x;
    float o1 = (x1v - mean) * rs * gg.y + bb.y;
    unsigned int pk = ((unsigned int)f2bf(o1) << 16) | f2bf(o0);
    ((unsigned int*)xmidb)[tg * 64 + lane] = pk;
  }
}

// ---------------------------------------------------------------------------
// mlp_tf (proven round 10/12): mlp with LN1 output kept in swizzled LDS,
// then fused transform of the NEXT block. Writes Vxb+lg for the next attn.
// ---------------------------------------------------------------------------
__global__ __launch_bounds__(256) void mlp_tf(
    const ushort_t* __restrict__ xmb, const ushort_t* __restrict__ W1sw,
    const float* __restrict__ b1, const ushort_t* __restrict__ W2sw,
    const float* __restrict__ b2, const float* __restrict__ g1,
    const float* __restrict__ be1, float* __restrict__ outf, int n, int wf32,
    const ushort_t* __restrict__ Bsw, ushort_t* __restrict__ Vxb,
    float* __restrict__ lg) {
  __shared__ char S[65536];
  char* Wlds = S;
  char* Hlds = S + 32768;
  char* Xout = S + 49152;
  int t = threadIdx.x, l = t & 63, w = t >> 6;
  size_t r0 = (size_t)blockIdx.x * 64;
#pragma unroll
  for (int it = 0; it < 8; ++it) {
    int off = it * 4096 + w * 1024 + l * 16;
    gload16((const char*)W1sw + off, Wlds + off);
  }
  float b1v[8], b2v[8], g1v[8], be1v[8];
#pragma unroll
  for (int ct = 0; ct < 8; ++ct) {
    int c = ct * 16 + (l & 15);
    b1v[ct] = b1[c]; b2v[ct] = b2[c]; g1v[ct] = g1[c]; be1v[ct] = be1[c];
  }
  __syncthreads();

  int swz = (l & 7) << 4;
  int lbase = (l & 15) * 256 + (l >> 4) * 16;
  int hbase = w * 4096;
  f32x4 acc[8];
#pragma unroll
  for (int ct = 0; ct < 8; ++ct) acc[ct] = (f32x4){b1v[ct], b1v[ct], b1v[ct], b1v[ct]};
  const ushort_t* abase = xmb + (r0 + w * 16 + (l & 15)) * 128 + (l >> 4) * 8;
#pragma unroll
  for (int kk = 0; kk < 4; ++kk) {
    bf16x8 a = *(const bf16x8*)(abase + kk * 32);
#pragma unroll
    for (int ct = 0; ct < 8; ++ct) {
      bf16x8 b = *(const bf16x8*)(Wlds + ((ct * 4096 + kk * 64 + lbase) ^ swz));
      acc[ct] = __builtin_amdgcn_mfma_f32_16x16x32_bf16(a, b, acc[ct], 0, 0, 0);
    }
  }
#pragma unroll
  for (int ct = 0; ct < 8; ++ct) {
    int c2 = (ct * 16 + (l & 15)) * 2;
#pragma unroll
    for (int j = 0; j < 4; ++j) {
      int rl = (l >> 4) * 4 + j;
      int addr = hbase + ((rl * 256 + c2) ^ ((rl & 7) << 4));
      *(ushort_t*)(Hlds + addr) = f2bf(fmaxf(acc[ct][j], 0.f));
    }
  }
  __syncthreads();
#pragma unroll
  for (int it = 0; it < 8; ++it) {
    int off = it * 4096 + w * 1024 + l * 16;
    gload16((const char*)W2sw + off, Wlds + off);
  }
  __syncthreads();

  f32x4 acc2[8];
#pragma unroll
  for (int ct = 0; ct < 8; ++ct) acc2[ct] = (f32x4){b2v[ct], b2v[ct], b2v[ct], b2v[ct]};
#pragma unroll
  for (int kk = 0; kk < 4; ++kk) {
    bf16x8 a = *(const bf16x8*)(Hlds + (hbase + ((lbase + kk * 64) ^ swz)));
#pragma unroll
    for (int ct = 0; ct < 8; ++ct) {
      bf16x8 b = *(const bf16x8*)(Wlds + ((ct * 4096 + kk * 64 + lbase) ^ swz));
      acc2[ct] = __builtin_amdgcn_mfma_f32_16x16x32_bf16(a, b, acc2[ct], 0, 0, 0);
    }
  }
  size_t rbase = r0 + w * 16 + (l >> 4) * 4;
  float s1[4] = {0.f, 0.f, 0.f, 0.f}, s2[4] = {0.f, 0.f, 0.f, 0.f};
#pragma unroll
  for (int ct = 0; ct < 8; ++ct) {
    int c = ct * 16 + (l & 15);
#pragma unroll
    for (int j = 0; j < 4; ++j) {
      float x = bf2f(xmb[(rbase + j) * 128 + c]);
      float y = acc2[ct][j] + x;
      acc2[ct][j] = y;
      s1[j] += y;
      s2[j] += y * y;
    }
  }
#pragma unroll
  for (int off = 1; off < 16; off <<= 1) {
#pragma unroll
    for (int j = 0; j < 4; ++j) {
      s1[j] += __shfl_xor(s1[j], off);
      s2[j] += __shfl_xor(s2[j], off);
    }
  }
  float mean[4], rs[4];
#pragma unroll
  for (int j = 0; j < 4; ++j) {
    mean[j] = s1[j] * (1.f / 128.f);
    float var = s2[j] * (1.f / 128.f) - mean[j] * mean[j];
    rs[j] = rsqrtf(var + 1e-5f);
  }
#pragma unroll
  for (int ct = 0; ct < 8; ++ct) {
    int c = ct * 16 + (l & 15);
    int c2 = c * 2;
#pragma unroll
    for (int j = 0; j < 4; ++j) {
      float o = fmaxf((acc2[ct][j] - mean[j]) * rs[j] * g1v[ct] + be1v[ct], 0.f);
      int rl = (l >> 4) * 4 + j;
      int addr = hbase + ((rl * 256 + c2) ^ ((rl & 7) << 4));
      *(ushort_t*)(Xout + addr) = f2bf(o);
      size_t row = rbase + j;
      if (wf32 && row < (size_t)n) outf[row * 128 + c] = o;
    }
  }
  __syncthreads();  // Xout complete; Wlds/Hlds dead

  char* Blds = S;
#pragma unroll
  for (int it = 0; it < 9; ++it) {
    int off = it * 4096 + w * 1024 + l * 16;
    gload16((const char*)Bsw + off, Blds + off);
  }
  __syncthreads();

  f32x4 ta[9];
#pragma unroll
  for (int ct = 0; ct < 9; ++ct) ta[ct] = (f32x4){0.f, 0.f, 0.f, 0.f};
#pragma unroll
  for (int kk = 0; kk < 4; ++kk) {
    bf16x8 a = *(const bf16x8*)(Xout + (hbase + ((lbase + kk * 64) ^ swz)));
#pragma unroll
    for (int ct = 0; ct < 9; ++ct) {
      bf16x8 b = *(const bf16x8*)(Blds + ((ct * 4096 + kk * 64 + lbase) ^ swz));
      ta[ct] = __builtin_amdgcn_mfma_f32_16x16x32_bf16(a, b, ta[ct], 0, 0, 0);
    }
  }
  if ((l & 15) < 4) {
    size_t rb = r0 + w * 16 + (l >> 4) * 4;
#pragma unroll
    for (int j = 0; j < 4; ++j) lg[(rb + j) * 4 + (l & 15)] = ta[8][j];
  }
  __syncthreads();
  char* Olds = Xout;
  int row64 = w * 16 + (l >> 4) * 4;
#pragma unroll
  for (int ct = 0; ct < 8; ++ct) {
    int c2 = (ct * 16 + (l & 15)) * 2;
#pragma unroll
    for (int j = 0; j < 4; ++j) {
      int r = row64 + j;
      int addr = (r * 256 + c2) ^ ((r & 0xC) << 3);
      *(ushort_t*)(Olds + addr) = f2bf(ta[ct][j]);
    }
  }
  __syncthreads();
#pragma unroll
  for (int it = 0; it < 4; ++it) {
    int L = it * 4096 + t * 16;
    int r = L >> 8;
    int phys = L ^ ((r & 0xC) << 3);
    *(uint4*)((char*)Vxb + r0 * 256 + L) = *(const uint4*)(Olds + phys);
  }
}

// ---------------------------------------------------------------------------
// mlp (MFMA, proven) — final block only (f32 out)
// ---------------------------------------------------------------------------
__global__ __launch_bounds__(256) void mlp_k(
    const ushort_t* __restrict__ xmb, const ushort_t* __restrict__ W1sw,
    const float* __restrict__ b1, const ushort_t* __restrict__ W2sw,
    const float* __restrict__ b2, const float* __restrict__ g1,
    const float* __restrict__ be1, float* __restrict__ outf, int n) {
  __shared__ char Wlds[32768];
  __shared__ char Hlds[16384];
  int t = threadIdx.x, l = t & 63, w = t >> 6;
  size_t r0 = (size_t)blockIdx.x * 64;
#pragma unroll
  for (int it = 0; it < 8; ++it) {
    int off = it * 4096 + w * 1024 + l * 16;
    gload16((const char*)W1sw + off, Wlds + off);
  }
  float b1v[8], b2v[8], g1v[8], be1v[8];
#pragma unroll
  for (int ct = 0; ct < 8; ++ct) {
    int c = ct * 16 + (l & 15);
    b1v[ct] = b1[c]; b2v[ct] = b2[c]; g1v[ct] = g1[c]; be1v[ct] = be1[c];
  }
  __syncthreads();

  int swz = (l & 7) << 4;
  int lbase = (l & 15) * 256 + (l >> 4) * 16;
  f32x4 acc[8];
#pragma unroll
  for (int ct = 0; ct < 8; ++ct) acc[ct] = (f32x4){b1v[ct], b1v[ct], b1v[ct], b1v[ct]};
  const ushort_t* abase = xmb + (r0 + w * 16 + (l & 15)) * 128 + (l >> 4) * 8;
#pragma unroll
  for (int kk = 0; kk < 4; ++kk) {
    bf16x8 a = *(const bf16x8*)(abase + kk * 32);
#pragma unroll
    for (int ct = 0; ct < 8; ++ct) {
      bf16x8 b = *(const bf16x8*)(Wlds + ((ct * 4096 + kk * 64 + lbase) ^ swz));
      acc[ct] = __builtin_amdgcn_mfma_f32_16x16x32_bf16(a, b, acc[ct], 0, 0, 0);
    }
  }
  int hbase = w * 4096;
#pragma unroll
  for (int ct = 0; ct < 8; ++ct) {
    int c2 = (ct * 16 + (l & 15)) * 2;
#pragma unroll
    for (int j = 0; j < 4; ++j) {
      int rl = (l >> 4) * 4 + j;
      int addr = hbase + ((rl * 256 + c2) ^ ((rl & 7) << 4));
      *(ushort_t*)(Hlds + addr) = f2bf(fmaxf(acc[ct][j], 0.f));
    }
  }
  __syncthreads();
#pragma unroll
  for (int it = 0; it < 8; ++it) {
    int off = it * 4096 + w * 1024 + l * 16;
    gload16((const char*)W2sw + off, Wlds + off);
  }
  __syncthreads();

  f32x4 acc2[8];
#pragma unroll
  for (int ct = 0; ct < 8; ++ct) acc2[ct] = (f32x4){b2v[ct], b2v[ct], b2v[ct], b2v[ct]};
#pragma unroll
  for (int kk = 0; kk < 4; ++kk) {
    bf16x8 a = *(const bf16x8*)(Hlds + (hbase + ((lbase + kk * 64) ^ swz)));
#pragma unroll
    for (int ct = 0; ct < 8; ++ct) {
      bf16x8 b = *(const bf16x8*)(Wlds + ((ct * 4096 + kk * 64 + lbase) ^ swz));
      acc2[ct] = __builtin_amdgcn_mfma_f32_16x16x32_bf16(a, b, acc2[ct], 0, 0, 0);
    }
  }
  size_t rbase = r0 + w * 16 + (l >> 4) * 4;
  float s1[4] = {0.f, 0.f, 0.f, 0.f}, s2[4] = {0.f, 0.f, 0.f, 0.f};
#pragma unroll
  for (int ct = 0; ct < 8; ++ct) {
    int c = ct * 16 + (l & 15);
#pragma unroll
    for (int j = 0; j < 4; ++j) {
      float x = bf2f(xmb[(rbase + j) * 128 + c]);
      float y = acc2[ct][j] + x;
      acc2[ct][j] = y;
      s1[j] += y;
      s2[j] += y * y;
    }
  }
#pragma unroll
  for (int off = 1; off < 16; off <<= 1) {
#pragma unroll
    for (int j = 0; j < 4; ++j) {
      s1[j] += __shfl_xor(s1[j], off);
      s2[j] += __shfl_xor(s2[j], off);
    }
  }
  float mean[4], rs[4];
#pragma unroll
  for (int j = 0; j < 4; ++j) {
    mean[j] = s1[j] * (1.f / 128.f);
    float var = s2[j] * (1.f / 128.f) - mean[j] * mean[j];
    rs[j] = rsqrtf(var + 1e-5f);
  }
#pragma unroll
  for (int ct = 0; ct < 8; ++ct) {
    int c = ct * 16 + (l & 15);
#pragma unroll
    for (int j = 0; j < 4; ++j) {
      float o = fmaxf((acc2[ct][j] - mean[j]) * rs[j] * g1v[ct] + be1v[ct], 0.f);
      size_t row = rbase + j;
      if (row < (size_t)n) outf[row * 128 + c] = o;
    }
  }
}

// ---------------------------------------------------------------------------
extern "C" void kernel_launch(void* const* d_in, const int* in_sizes, int n_in,
                              void* d_out, int out_size, void* d_ws, size_t ws_size,
                              hipStream_t stream) {
  const float* x0_in = (const float*)d_in[0];
  const float* Kw  = (const float*)d_in[1];
  const float* Vw  = (const float*)d_in[2];
  const float* Qw  = (const float*)d_in[3];
  const float* W1  = (const float*)d_in[4];
  const float* b1  = (const float*)d_in[5];
  const float* W2  = (const float*)d_in[6];
  const float* b2  = (const float*)d_in[7];
  const float* ln0g = (const float*)d_in[8];
  const float* ln0b = (const float*)d_in[9];
  const float* ln1g = (const float*)d_in[10];
  const float* ln1b = (const float*)d_in[11];
  const int* node_idx  = (const int*)d_in[12];
  const int* hedge_idx = (const int*)d_in[13];

  float* out = (float*)d_out;
  float* x0_out = out;
  float* x1_out = out + (size_t)N_NODES * 128;

  char* w = (char*)d_ws;
  auto alloc = [&](size_t bytes) -> void* {
    void* p = (void*)w;
    w += (bytes + 255) & ~(size_t)255;
    return p;
  };
  ushort_t* Vvqsw = (ushort_t*)alloc(4 * 18432 * 2);
  ushort_t* W1sw  = (ushort_t*)alloc(4 * 16384 * 2);
  ushort_t* W2sw  = (ushort_t*)alloc(4 * 16384 * 2);
  ushort_t* x0b   = (ushort_t*)alloc((size_t)NPN * 128 * 2);
  ushort_t* Vxb   = (ushort_t*)alloc((size_t)NPN * 128 * 2);
  float*    lg    = (float*)alloc((size_t)NPN * 4 * 4);
  ushort_t* xmidb = (ushort_t*)alloc((size_t)NPN * 128 * 2);
  int2* segH  = (int2*)alloc((size_t)N_HEDGES * 8);
  int2* segN  = (int2*)alloc((size_t)N_NODES * 8);
  int* pinsH  = (int*)alloc(N_PINS * 4);
  int* pinsN  = (int*)alloc(N_PINS * 4);
  int* ovfH   = (int*)alloc(OVF_CAP * 4);
  int* ovfN   = (int*)alloc(OVF_CAP * 4);
  unsigned* rank2 = (unsigned*)alloc((size_t)N_PINS * 4);
  int* zbase  = (int*)alloc((size_t)(N_HEDGES + N_NODES + 4) * 4);
  int* cntH = zbase;
  int* cntN = cntH + N_HEDGES;
  int* gctr = cntN + N_NODES;  // [gH, gN, ovfcntH, ovfcntN]

  hipMemsetAsync(zbase, 0, (size_t)(N_HEDGES + N_NODES + 4) * 4, stream);

  fused_front<<<2048, 256, 0, stream>>>(x0_in, x0b, node_idx, hedge_idx, cntN, cntH,
                                        rank2, Kw, Vw, Qw, W1, W2, Vvqsw, W1sw, W2sw);
  scan_tf<<<SCAN_B + TB, 256, 0, stream>>>(cntH, segH, ovfH, cntN, segN, ovfN,
                                           gctr, x0b, Vvqsw, Vxb, lg);
  csr_fill<<<(N_PINS + 255) / 256, 256, 0, stream>>>(node_idx, hedge_idx, rank2,
                                                     segN, segH, pinsN, pinsH);

  const int2* segs[4] = {segH, segN, segH, segN};
  const int* pinss[4] = {pinsH, pinsN, pinsH, pinsN};
  int n_tgts[4] = {N_HEDGES, N_NODES, N_HEDGES, N_NODES};
  const int mbH = (N_HEDGES + 7) / 8;     // L=32: 8 targets/block
  const int mbN = (N_NODES + 15) / 16;    // L=16: 16 targets/block

  for (int b = 0; b < 4; ++b) {
    int n_tgt = n_tgts[b];
    if (b & 1) {
      attn_g<16><<<mbN + 32, 256, 0, stream>>>(Vxb, lg, segs[b], pinss[b],
                                               Qw + b * 128, ln0g + b * 128,
                                               ln0b + b * 128, xmidb, n_tgt,
                                               mbN, ovfN, gctr + 3);
    } else {
      attn_g<32><<<mbH + 32, 256, 0, stream>>>(Vxb, lg, segs[b], pinss[b],
                                               Qw + b * 128, ln0g + b * 128,
                                               ln0b + b * 128, xmidb, n_tgt,
                                               mbH, ovfH, gctr + 2);
    }
    if (b < 3) {
      int wf32 = (b == 2) ? 1 : 0;
      float* of = (b == 2) ? x1_out : nullptr;
      mlp_tf<<<(n_tgt + 63) / 64, 256, 0, stream>>>(
          xmidb, W1sw + b * 16384, b1 + b * 128, W2sw + b * 16384, b2 + b * 128,
          ln1g + b * 128, ln1b + b * 128, of, n_tgt, wf32,
          Vvqsw + (b + 1) * 18432, Vxb, lg);
    } else {
      mlp_k<<<(n_tgt + 63) / 64, 256, 0, stream>>>(
          xmidb, W1sw + b * 16384, b1 + b * 128, W2sw + b * 16384, b2 + b * 128,
          ln1g + b * 128, ln1b + b * 128, x0_out, n_tgt);
    }
  }
}